// Round 2
// baseline (887.651 us; speedup 1.0000x reference)
//
#include <hip/hip_runtime.h>
#include <hip/hip_bf16.h>

typedef __bf16 bf16_t;
typedef bf16_t bf16x8 __attribute__((ext_vector_type(8)));
typedef bf16_t bf16x4 __attribute__((ext_vector_type(4)));
typedef float  floatx4 __attribute__((ext_vector_type(4)));

#define NB    32
#define NV    207
#define NL    12
#define NROW  2484          // NV*NL rows per batch
#define RT    16            // rows per workgroup tile
#define LDSROW 136          // padded row stride in elems (128 + 8)

// ---- kernel 0: transpose fp32 weights into bf16 ws: wt[mat][e][d] = W[comp][d][e]
// mats 0..3 = WQ comps, 4..7 = WK, 8..11 = WV
__global__ void transpose_w(const float* __restrict__ wq,
                            const float* __restrict__ wk,
                            const float* __restrict__ wv,
                            bf16_t* __restrict__ wt) {
  int idx = blockIdx.x * 256 + threadIdx.x;
  if (idx >= 12 * 128 * 128) return;
  int mat = idx >> 14;
  int e   = (idx >> 7) & 127;
  int d   = idx & 127;
  const float* src = (mat < 4) ? wq : ((mat < 8) ? wk : wv);
  wt[idx] = (bf16_t)src[((mat & 3) << 14) + (d << 7) + e];
}

__device__ __forceinline__ bf16x8 ldf8(const float* p) {
  floatx4 a = *(const floatx4*)p;
  floatx4 b = *(const floatx4*)(p + 4);
  bf16x8 r;
  r[0] = (bf16_t)a[0]; r[1] = (bf16_t)a[1]; r[2] = (bf16_t)a[2]; r[3] = (bf16_t)a[3];
  r[4] = (bf16_t)b[0]; r[5] = (bf16_t)b[1]; r[6] = (bf16_t)b[2]; r[7] = (bf16_t)b[3];
  return r;
}

__global__ __launch_bounds__(256)
void fused_attn(const float* __restrict__ x,
                const bf16_t* __restrict__ wt,
                const float* __restrict__ bq,
                const float* __restrict__ bk,
                const float* __restrict__ bv,
                const float* __restrict__ aw,
                float* __restrict__ out) {
  __shared__ bf16_t qkv[12 * RT * LDSROW];   // [mat][row][e] padded
  __shared__ unsigned rowbase[RT];           // x elem offset of GEMM-input row
  __shared__ float ew[32];                   // exp(attn_weights)

  const int b   = blockIdx.y;
  const int n0  = blockIdx.x * RT;
  const int tid = threadIdx.x;

  if (tid < 32) {
    ew[tid] = __expf(aw[tid]);
    if (tid < RT) {
      int n = n0 + tid;
      if (n >= NROW) n = NROW - 1;          // clamp edge rows (garbage, never written)
      int v = n % NV;
      int l = n / NV;
      rowbase[tid] = (unsigned)(b * NROW + v * NL + l) * 512u;
    }
  }
  __syncthreads();

  // ---------------- GEMM phase: QKV for RT rows into LDS ----------------
  {
    const int lane = tid & 63;
    const int wave = tid >> 6;
    const int quad = lane >> 4;
    const int l16  = lane & 15;
    const unsigned xoff = rowbase[l16];

    for (int c = wave; c < 96; c += 4) {     // 12 mats x 8 e-tiles
      const int mat  = c >> 3;
      const int e0   = (c & 7) << 4;
      const int comp = mat & 3;

      // A = WT[mat]: lane holds A[e = e0+l16][d = k0 + quad*8 + j]
      const bf16_t* wrow = wt + (mat << 14) + ((e0 + l16) << 7) + quad * 8;
      bf16x8 a0 = *(const bf16x8*)(wrow);
      bf16x8 a1 = *(const bf16x8*)(wrow + 32);
      bf16x8 a2 = *(const bf16x8*)(wrow + 64);
      bf16x8 a3 = *(const bf16x8*)(wrow + 96);

      // B = x rows (fp32 -> bf16): lane holds B[d = k0 + quad*8 + j][n = l16]
      const float* xrow = x + xoff + comp * 128 + quad * 8;
      bf16x8 b0 = ldf8(xrow);
      bf16x8 b1 = ldf8(xrow + 32);
      bf16x8 b2 = ldf8(xrow + 64);
      bf16x8 b3 = ldf8(xrow + 96);

      // C init = bias[e] broadcast over n; lane holds D[e = e0+quad*4+r][n = l16]
      const float* bias = ((mat < 4) ? bq : (mat < 8) ? bk : bv) + comp * 128 + e0 + quad * 4;
      floatx4 acc;
      acc[0] = bias[0];
      acc[1] = bias[1];
      acc[2] = bias[2];
      acc[3] = bias[3];

      acc = __builtin_amdgcn_mfma_f32_16x16x32_bf16(a0, b0, acc, 0, 0, 0);
      acc = __builtin_amdgcn_mfma_f32_16x16x32_bf16(a1, b1, acc, 0, 0, 0);
      acc = __builtin_amdgcn_mfma_f32_16x16x32_bf16(a2, b2, acc, 0, 0, 0);
      acc = __builtin_amdgcn_mfma_f32_16x16x32_bf16(a3, b3, acc, 0, 0, 0);

      bf16x4 st;
      st[0] = (bf16_t)acc[0];
      st[1] = (bf16_t)acc[1];
      st[2] = (bf16_t)acc[2];
      st[3] = (bf16_t)acc[3];
      *(bf16x4*)(&qkv[(mat * RT + l16) * LDSROW + e0 + quad * 4]) = st;
    }
  }
  __syncthreads();

  // ---------------- attention phase ----------------
  // thread = (row, head, g); g handles components {2g, 2g+1}
  const int g   = tid & 1;
  const int h   = (tid >> 1) & 7;
  const int row = tid >> 4;
  const int n   = n0 + row;
  if (n >= NROW) return;
  const int hb = h * 16;

  // load q for my two components
  float q[2][16];
#pragma unroll
  for (int ii = 0; ii < 2; ++ii) {
    const int i = g * 2 + ii;
    const bf16_t* p = &qkv[(i * RT + row) * LDSROW + hb];
    bf16x8 u0 = *(const bf16x8*)(p);
    bf16x8 u1 = *(const bf16x8*)(p + 8);
#pragma unroll
    for (int d = 0; d < 8; ++d) { q[ii][d] = (float)u0[d]; q[ii][8 + d] = (float)u1[d]; }
  }

  // scores vs ALL 4 k's (self-score computed but masked out later)
  float sc[2][4];
#pragma unroll
  for (int j = 0; j < 4; ++j) {
    const bf16_t* p = &qkv[((4 + j) * RT + row) * LDSROW + hb];
    bf16x8 u0 = *(const bf16x8*)(p);
    bf16x8 u1 = *(const bf16x8*)(p + 8);
    float kk[16];
#pragma unroll
    for (int d = 0; d < 8; ++d) { kk[d] = (float)u0[d]; kk[8 + d] = (float)u1[d]; }
#pragma unroll
    for (int ii = 0; ii < 2; ++ii) {
      float s = 0.f;
#pragma unroll
      for (int d = 0; d < 16; ++d) s += q[ii][d] * kk[d];
      sc[ii][j] = s * 0.25f;
    }
  }

  // per-pair coefficients cf[ii][j] = (1/sum_w) * sum_{subsets s containing j} w_s * e_j / denom_s
  float cf[2][4];
#pragma unroll
  for (int ii = 0; ii < 2; ++ii) {
    const int i = g * 2 + ii;
    // membership bitmask over s=0..7 for each j (bit s set if j in MASKS[i][s])
    unsigned mb0 = (i == 0) ? 0u : 0xF0u;
    unsigned mb1 = (i == 1) ? 0u : ((i == 0) ? 0xF0u : 0xCCu);
    unsigned mb2 = (i == 3) ? 0xAAu : ((i == 2) ? 0u : 0xCCu);
    unsigned mb3 = (i == 3) ? 0u : 0xAAu;
    float e0 = __expf(sc[ii][0]);
    float e1 = __expf(sc[ii][1]);
    float e2 = __expf(sc[ii][2]);
    float e3 = __expf(sc[ii][3]);
    float c0 = 0.f, c1 = 0.f, c2 = 0.f, c3 = 0.f, sumw = 0.f;
#pragma unroll
    for (int s = 1; s < 8; ++s) {
      float w = ew[i * 8 + s];
      float denom = 0.f;
      denom += ((mb0 >> s) & 1) ? e0 : 0.f;
      denom += ((mb1 >> s) & 1) ? e1 : 0.f;
      denom += ((mb2 >> s) & 1) ? e2 : 0.f;
      denom += ((mb3 >> s) & 1) ? e3 : 0.f;
      float r = w / denom;
      c0 += ((mb0 >> s) & 1) ? r * e0 : 0.f;
      c1 += ((mb1 >> s) & 1) ? r * e1 : 0.f;
      c2 += ((mb2 >> s) & 1) ? r * e2 : 0.f;
      c3 += ((mb3 >> s) & 1) ? r * e3 : 0.f;
      sumw += w;
    }
    float inv = 1.0f / sumw;
    cf[ii][0] = c0 * inv;
    cf[ii][1] = c1 * inv;
    cf[ii][2] = c2 * inv;
    cf[ii][3] = c3 * inv;   // cf[ii][i] == 0 by construction
  }

  // weighted V combine
  float acc[2][16];
#pragma unroll
  for (int ii = 0; ii < 2; ++ii)
#pragma unroll
    for (int d = 0; d < 16; ++d) acc[ii][d] = 0.f;
#pragma unroll
  for (int j = 0; j < 4; ++j) {
    const bf16_t* p = &qkv[((8 + j) * RT + row) * LDSROW + hb];
    bf16x8 u0 = *(const bf16x8*)(p);
    bf16x8 u1 = *(const bf16x8*)(p + 8);
    float vv[16];
#pragma unroll
    for (int d = 0; d < 8; ++d) { vv[d] = (float)u0[d]; vv[8 + d] = (float)u1[d]; }
#pragma unroll
    for (int ii = 0; ii < 2; ++ii) {
      const float cc = cf[ii][j];
#pragma unroll
      for (int d = 0; d < 16; ++d) acc[ii][d] += cc * vv[d];
    }
  }

  // epilogue: add residual (fp32), write out (fp32); both contiguous in n
#pragma unroll
  for (int ii = 0; ii < 2; ++ii) {
    const int i = g * 2 + ii;
    const unsigned o = (((unsigned)(b * NROW + n) * 4u + (unsigned)i) << 7) + (unsigned)hb;
    const float* rp = x + o;
    floatx4 r0 = *(const floatx4*)(rp);
    floatx4 r1 = *(const floatx4*)(rp + 4);
    floatx4 r2 = *(const floatx4*)(rp + 8);
    floatx4 r3 = *(const floatx4*)(rp + 12);
    floatx4 s0, s1, s2, s3;
#pragma unroll
    for (int d = 0; d < 4; ++d) {
      s0[d] = acc[ii][d]      + r0[d];
      s1[d] = acc[ii][4 + d]  + r1[d];
      s2[d] = acc[ii][8 + d]  + r2[d];
      s3[d] = acc[ii][12 + d] + r3[d];
    }
    *(floatx4*)(out + o)      = s0;
    *(floatx4*)(out + o + 4)  = s1;
    *(floatx4*)(out + o + 8)  = s2;
    *(floatx4*)(out + o + 12) = s3;
  }
}

extern "C" void kernel_launch(void* const* d_in, const int* in_sizes, int n_in,
                              void* d_out, int out_size, void* d_ws, size_t ws_size,
                              hipStream_t stream) {
  const float* x  = (const float*)d_in[0];
  const float* wq = (const float*)d_in[1];
  const float* bq = (const float*)d_in[2];
  const float* wk = (const float*)d_in[3];
  const float* bk = (const float*)d_in[4];
  const float* wv = (const float*)d_in[5];
  const float* bv = (const float*)d_in[6];
  const float* aw = (const float*)d_in[7];
  float* out = (float*)d_out;
  bf16_t* wt = (bf16_t*)d_ws;    // 12*128*128 bf16 = 384 KiB

  transpose_w<<<dim3(768), dim3(256), 0, stream>>>(wq, wk, wv, wt);

  dim3 grid((NROW + RT - 1) / RT, NB);   // 156 x 32
  fused_attn<<<grid, dim3(256), 0, stream>>>(x, wt, bq, bk, bv, aw, out);
}

// Round 3
// 543.304 us; speedup vs baseline: 1.6338x; 1.6338x over previous
//
#include <hip/hip_runtime.h>
#include <hip/hip_bf16.h>

typedef __bf16 bf16_t;
typedef bf16_t bf16x8 __attribute__((ext_vector_type(8)));
typedef bf16_t bf16x4 __attribute__((ext_vector_type(4)));
typedef float  floatx4 __attribute__((ext_vector_type(4)));

#define NB    32
#define NV    207
#define NL    12
#define NROW  2484          // NV*NL rows per batch
#define RT    16            // rows per workgroup tile
#define LDSROW 136          // padded row stride in elems (128 + 8)

// ---- kernel 0: transpose fp32 weights into bf16 ws: wt[mat][e][d] = W[comp][d][e]
// mats 0..3 = WQ comps, 4..7 = WK, 8..11 = WV
__global__ void transpose_w(const float* __restrict__ wq,
                            const float* __restrict__ wk,
                            const float* __restrict__ wv,
                            bf16_t* __restrict__ wt) {
  int idx = blockIdx.x * 256 + threadIdx.x;
  if (idx >= 12 * 128 * 128) return;
  int mat = idx >> 14;
  int e   = (idx >> 7) & 127;
  int d   = idx & 127;
  const float* src = (mat < 4) ? wq : ((mat < 8) ? wk : wv);
  wt[idx] = (bf16_t)src[((mat & 3) << 14) + (d << 7) + e];
}

__device__ __forceinline__ bf16x8 ldf8(const float* p) {
  floatx4 a = *(const floatx4*)p;
  floatx4 b = *(const floatx4*)(p + 4);
  bf16x8 r;
  r[0] = (bf16_t)a[0]; r[1] = (bf16_t)a[1]; r[2] = (bf16_t)a[2]; r[3] = (bf16_t)a[3];
  r[4] = (bf16_t)b[0]; r[5] = (bf16_t)b[1]; r[6] = (bf16_t)b[2]; r[7] = (bf16_t)b[3];
  return r;
}

__global__ __launch_bounds__(256)
void fused_attn(const float* __restrict__ x,
                const bf16_t* __restrict__ wt,
                const float* __restrict__ bq,
                const float* __restrict__ bk,
                const float* __restrict__ bv,
                const float* __restrict__ aw,
                float* __restrict__ out) {
  __shared__ bf16_t qkv[12 * RT * LDSROW];   // [mat][row][e] padded
  __shared__ float ew[32];                   // exp(attn_weights)

  const int b   = blockIdx.y;
  const int n0  = blockIdx.x * RT;
  const int tid = threadIdx.x;

  if (tid < 32) ew[tid] = __expf(aw[tid]);

  // ---------------- GEMM phase: QKV for RT rows into LDS ----------------
  // wave w owns component w: B fragments loaded ONCE, then 3 mats x 8 e-tiles
  {
    const int lane = tid & 63;
    const int w    = tid >> 6;          // wave id == component
    const int quad = lane >> 4;
    const int l16  = lane & 15;

    int n = n0 + l16;
    if (n >= NROW) n = NROW - 1;        // clamp edge rows (garbage, never written)
    const int v = n % NV;
    const int l = n / NV;

    // B = x rows (fp32 -> bf16): lane holds B[d = k0 + quad*8 + j][n = l16]
    const float* xrow = x + ((unsigned)(b * NROW + v * NL + l) << 9) + w * 128 + quad * 8;
    const bf16x8 b0 = ldf8(xrow);
    const bf16x8 b1 = ldf8(xrow + 32);
    const bf16x8 b2 = ldf8(xrow + 64);
    const bf16x8 b3 = ldf8(xrow + 96);

#pragma unroll
    for (int m = 0; m < 3; ++m) {
      const int mat = w + (m << 2);     // WQ/WK/WV for comp w
      const bf16_t* wbase = wt + (mat << 14) + (l16 << 7) + quad * 8;
      const float*  bias  = ((m == 0) ? bq : (m == 1) ? bk : bv) + w * 128 + quad * 4;
      bf16_t* lbase = &qkv[(mat * RT + l16) * LDSROW + quad * 4];

#pragma unroll 4
      for (int e0t = 0; e0t < 8; ++e0t) {
        const int e0 = e0t << 4;
        // A = WT[mat]: lane holds A[e = e0+l16][d = k0 + quad*8 + j]
        const bf16_t* wrow = wbase + (e0 << 7);
        bf16x8 a0 = *(const bf16x8*)(wrow);
        bf16x8 a1 = *(const bf16x8*)(wrow + 32);
        bf16x8 a2 = *(const bf16x8*)(wrow + 64);
        bf16x8 a3 = *(const bf16x8*)(wrow + 96);

        // C init = bias[e]; lane holds D[e = e0+quad*4+r][n = l16]
        const float* bp = bias + e0;
        floatx4 acc;
        acc[0] = bp[0];
        acc[1] = bp[1];
        acc[2] = bp[2];
        acc[3] = bp[3];

        acc = __builtin_amdgcn_mfma_f32_16x16x32_bf16(a0, b0, acc, 0, 0, 0);
        acc = __builtin_amdgcn_mfma_f32_16x16x32_bf16(a1, b1, acc, 0, 0, 0);
        acc = __builtin_amdgcn_mfma_f32_16x16x32_bf16(a2, b2, acc, 0, 0, 0);
        acc = __builtin_amdgcn_mfma_f32_16x16x32_bf16(a3, b3, acc, 0, 0, 0);

        bf16x4 st;
        st[0] = (bf16_t)acc[0];
        st[1] = (bf16_t)acc[1];
        st[2] = (bf16_t)acc[2];
        st[3] = (bf16_t)acc[3];
        *(bf16x4*)(lbase + e0) = st;
      }
    }
  }
  __syncthreads();

  // ---------------- attention phase ----------------
  // thread = (row, head, g); g handles components {2g, 2g+1}
  const int g   = tid & 1;
  const int h   = (tid >> 1) & 7;
  const int row = tid >> 4;
  const int n   = n0 + row;
  if (n >= NROW) return;
  const int hb = h * 16;

  // load q for my two components
  float q[2][16];
#pragma unroll
  for (int ii = 0; ii < 2; ++ii) {
    const int i = g * 2 + ii;
    const bf16_t* p = &qkv[(i * RT + row) * LDSROW + hb];
    bf16x8 u0 = *(const bf16x8*)(p);
    bf16x8 u1 = *(const bf16x8*)(p + 8);
#pragma unroll
    for (int d = 0; d < 8; ++d) { q[ii][d] = (float)u0[d]; q[ii][8 + d] = (float)u1[d]; }
  }

  // scores vs ALL 4 k's (self-score computed but masked out later)
  float sc[2][4];
#pragma unroll
  for (int j = 0; j < 4; ++j) {
    const bf16_t* p = &qkv[((4 + j) * RT + row) * LDSROW + hb];
    bf16x8 u0 = *(const bf16x8*)(p);
    bf16x8 u1 = *(const bf16x8*)(p + 8);
    float kk[16];
#pragma unroll
    for (int d = 0; d < 8; ++d) { kk[d] = (float)u0[d]; kk[8 + d] = (float)u1[d]; }
#pragma unroll
    for (int ii = 0; ii < 2; ++ii) {
      float s = 0.f;
#pragma unroll
      for (int d = 0; d < 16; ++d) s += q[ii][d] * kk[d];
      sc[ii][j] = s * 0.25f;
    }
  }

  // per-pair coefficients cf[ii][j] = (1/sum_w) * sum_{subsets s containing j} w_s * e_j / denom_s
  float cf[2][4];
#pragma unroll
  for (int ii = 0; ii < 2; ++ii) {
    const int i = g * 2 + ii;
    // membership bitmask over s=0..7 for each j (bit s set if j in MASKS[i][s])
    unsigned mb0 = (i == 0) ? 0u : 0xF0u;
    unsigned mb1 = (i == 1) ? 0u : ((i == 0) ? 0xF0u : 0xCCu);
    unsigned mb2 = (i == 3) ? 0xAAu : ((i == 2) ? 0u : 0xCCu);
    unsigned mb3 = (i == 3) ? 0u : 0xAAu;
    float e0 = __expf(sc[ii][0]);
    float e1 = __expf(sc[ii][1]);
    float e2 = __expf(sc[ii][2]);
    float e3 = __expf(sc[ii][3]);
    float c0 = 0.f, c1 = 0.f, c2 = 0.f, c3 = 0.f, sumw = 0.f;
#pragma unroll
    for (int s = 1; s < 8; ++s) {
      float w = ew[i * 8 + s];
      float denom = 0.f;
      denom += ((mb0 >> s) & 1) ? e0 : 0.f;
      denom += ((mb1 >> s) & 1) ? e1 : 0.f;
      denom += ((mb2 >> s) & 1) ? e2 : 0.f;
      denom += ((mb3 >> s) & 1) ? e3 : 0.f;
      float r = w / denom;
      c0 += ((mb0 >> s) & 1) ? r * e0 : 0.f;
      c1 += ((mb1 >> s) & 1) ? r * e1 : 0.f;
      c2 += ((mb2 >> s) & 1) ? r * e2 : 0.f;
      c3 += ((mb3 >> s) & 1) ? r * e3 : 0.f;
      sumw += w;
    }
    float inv = 1.0f / sumw;
    cf[ii][0] = c0 * inv;
    cf[ii][1] = c1 * inv;
    cf[ii][2] = c2 * inv;
    cf[ii][3] = c3 * inv;   // cf[ii][i] == 0 by construction
  }

  // weighted V combine
  float acc[2][16];
#pragma unroll
  for (int ii = 0; ii < 2; ++ii)
#pragma unroll
    for (int d = 0; d < 16; ++d) acc[ii][d] = 0.f;
#pragma unroll
  for (int j = 0; j < 4; ++j) {
    const bf16_t* p = &qkv[((8 + j) * RT + row) * LDSROW + hb];
    bf16x8 u0 = *(const bf16x8*)(p);
    bf16x8 u1 = *(const bf16x8*)(p + 8);
    float vv[16];
#pragma unroll
    for (int d = 0; d < 8; ++d) { vv[d] = (float)u0[d]; vv[8 + d] = (float)u1[d]; }
#pragma unroll
    for (int ii = 0; ii < 2; ++ii) {
      const float cc = cf[ii][j];
#pragma unroll
      for (int d = 0; d < 16; ++d) acc[ii][d] += cc * vv[d];
    }
  }

  // epilogue: add residual (fp32), write out (fp32); both contiguous in n
#pragma unroll
  for (int ii = 0; ii < 2; ++ii) {
    const int i = g * 2 + ii;
    const unsigned o = (((unsigned)(b * NROW + n) * 4u + (unsigned)i) << 7) + (unsigned)hb;
    const float* rp = x + o;
    floatx4 r0 = *(const floatx4*)(rp);
    floatx4 r1 = *(const floatx4*)(rp + 4);
    floatx4 r2 = *(const floatx4*)(rp + 8);
    floatx4 r3 = *(const floatx4*)(rp + 12);
    floatx4 s0, s1, s2, s3;
#pragma unroll
    for (int d = 0; d < 4; ++d) {
      s0[d] = acc[ii][d]      + r0[d];
      s1[d] = acc[ii][4 + d]  + r1[d];
      s2[d] = acc[ii][8 + d]  + r2[d];
      s3[d] = acc[ii][12 + d] + r3[d];
    }
    *(floatx4*)(out + o)      = s0;
    *(floatx4*)(out + o + 4)  = s1;
    *(floatx4*)(out + o + 8)  = s2;
    *(floatx4*)(out + o + 12) = s3;
  }
}

extern "C" void kernel_launch(void* const* d_in, const int* in_sizes, int n_in,
                              void* d_out, int out_size, void* d_ws, size_t ws_size,
                              hipStream_t stream) {
  const float* x  = (const float*)d_in[0];
  const float* wq = (const float*)d_in[1];
  const float* bq = (const float*)d_in[2];
  const float* wk = (const float*)d_in[3];
  const float* bk = (const float*)d_in[4];
  const float* wv = (const float*)d_in[5];
  const float* bv = (const float*)d_in[6];
  const float* aw = (const float*)d_in[7];
  float* out = (float*)d_out;
  bf16_t* wt = (bf16_t*)d_ws;    // 12*128*128 bf16 = 384 KiB

  transpose_w<<<dim3(768), dim3(256), 0, stream>>>(wq, wk, wv, wt);

  dim3 grid((NROW + RT - 1) / RT, NB);   // 156 x 32
  fused_attn<<<grid, dim3(256), 0, stream>>>(x, wt, bq, bk, bv, aw, out);
}